// Round 3
// baseline (1478.215 us; speedup 1.0000x reference)
//
#include <hip/hip_runtime.h>
#include <hip/hip_bf16.h>

#define BB 32
#define TT 120
#define EE 300
#define HH 256
#define VV 32000
#define CC 512
#define GG 49      // 7*7
#define KIN 556    // E+H
#define CF 25088   // C*49

typedef __attribute__((ext_vector_type(8))) short bf16x8;
typedef __attribute__((ext_vector_type(4))) float f32x4;

// ---- packed-bf16 helpers ----
__device__ __forceinline__ float bpair_lo(unsigned int u) { return __uint_as_float(u << 16); }
__device__ __forceinline__ float bpair_hi(unsigned int u) { return __uint_as_float(u & 0xFFFF0000u); }

__device__ __forceinline__ unsigned int packbf(float a, float b) {
    union { __hip_bfloat16 h; unsigned short u; } ua, ub;
    ua.h = __float2bfloat16(a); ub.h = __float2bfloat16(b);
    return (unsigned int)ua.u | ((unsigned int)ub.u << 16);
}

#if defined(__has_builtin)
#  if __has_builtin(__builtin_amdgcn_fdot2_f32_bf16)
#    define USE_DOT2 1
#  endif
#endif
#ifndef USE_DOT2
#  define USE_DOT2 0
#endif

#if USE_DOT2
typedef __bf16 bf2_t __attribute__((ext_vector_type(2)));
__device__ __forceinline__ float dot2bf(unsigned int w, unsigned int h, float c) {
    return __builtin_amdgcn_fdot2_f32_bf16(__builtin_bit_cast(bf2_t, w),
                                           __builtin_bit_cast(bf2_t, h), c, false);
}
#else
__device__ __forceinline__ float dot2bf(unsigned int w, unsigned int h, float c) {
    c = fmaf(bpair_lo(w), bpair_lo(h), c);
    c = fmaf(bpair_hi(w), bpair_hi(h), c);
    return c;
}
#endif

// ---------------- mean pool: features [B,C,49] -> mean_f [B,C] ----------------
__global__ void k_meanpool(const float* __restrict__ features, float* __restrict__ mean_f) {
    int b = blockIdx.x;
    for (int c = threadIdx.x; c < CC; c += 256) {
        const float* p = features + (size_t)b * CF + (size_t)c * GG;
        float s = 0.f;
#pragma unroll
        for (int i = 0; i < GG; ++i) s += p[i];
        mean_f[b * CC + c] = s * (1.0f / 49.0f);
    }
}

// ---------------- h0 = mean_f @ W_init.T + b_init -> [B,H] ----------------
__global__ void k_h0(const float* __restrict__ mean_f, const float* __restrict__ W_init,
                     const float* __restrict__ b_init, float* __restrict__ h0) {
    __shared__ float mf[CC];
    int b = blockIdx.x;
    for (int i = threadIdx.x; i < CC; i += 256) mf[i] = mean_f[b * CC + i];
    __syncthreads();
    int h = threadIdx.x;
    const float* w = W_init + (size_t)h * CC;
    float s = 0.f;
    for (int k = 0; k < CC; k += 4) {
        float4 w4 = *(const float4*)(w + k);
        s += mf[k] * w4.x + mf[k + 1] * w4.y + mf[k + 2] * w4.z + mf[k + 3] * w4.w;
    }
    h0[b * HH + h] = s + b_init[h];
}

// ---------------- feat = f_flat @ W_fc2.T + b_fc2 -> [B,H] ----------------
// f_flat[b, p*512+c] = features[b*25088 + c*49 + p]
__global__ void __launch_bounds__(256) k_fc2(const float* __restrict__ features,
                                             const float* __restrict__ W_fc2,
                                             const float* __restrict__ b_fc2,
                                             float* __restrict__ feat) {
    int h = blockIdx.x;
    float acc[BB];
#pragma unroll
    for (int b = 0; b < BB; ++b) acc[b] = 0.f;
    const float* w = W_fc2 + (size_t)h * CF;
    for (int i = threadIdx.x; i < CF; i += 256) {
        float wv = w[i];
        int c = i & (CC - 1);
        int p = i >> 9;
        const float* f = features + c * GG + p;
#pragma unroll
        for (int b = 0; b < BB; ++b) acc[b] += wv * f[(size_t)b * CF];
    }
    __shared__ float red[4][BB];
    int lane = threadIdx.x & 63, wave = threadIdx.x >> 6;
#pragma unroll
    for (int b = 0; b < BB; ++b) {
        float v = acc[b];
        for (int off = 32; off > 0; off >>= 1) v += __shfl_down(v, off, 64);
        if (lane == 0) red[wave][b] = v;
    }
    __syncthreads();
    if (threadIdx.x < BB) {
        float s = red[0][threadIdx.x] + red[1][threadIdx.x] + red[2][threadIdx.x] + red[3][threadIdx.x];
        feat[threadIdx.x * HH + h] = s + b_fc2[h];
    }
}

// ---------------- gi[t,b,g] = [emb|feat] @ W_ih.T + b_ih -> [T,B,768] f32 ----------------
// grid (4 g-chunks, 120 t, 2 batch-halves), 256 threads
__global__ void __launch_bounds__(256) k_gi(const float* __restrict__ emb,
                                            const float* __restrict__ feat,
                                            const float* __restrict__ W_ih,
                                            const float* __restrict__ b_ih,
                                            float* __restrict__ gi) {
    int ch = blockIdx.x;   // 0..3
    int t  = blockIdx.y;   // 0..119
    int bh = blockIdx.z;   // 0..1
    __shared__ float x[16][KIN + 1];   // 35.6 KB
    for (int i = threadIdx.x; i < 16 * KIN; i += 256) {
        int r = i / KIN, c = i - r * KIN;
        int bg = bh * 16 + r;
        x[r][c] = (c < EE) ? emb[(size_t)bg * TT * EE + (size_t)t * EE + c]
                           : feat[bg * HH + (c - EE)];
    }
    __syncthreads();
    int bloc = threadIdx.x & 15;
    int jj   = threadIdx.x >> 4;        // 0..15
    int g0   = ch * 192 + jj;
    float acc[12];
#pragma unroll
    for (int i = 0; i < 12; ++i) acc[i] = 0.f;
    for (int k = 0; k < KIN; k += 4) {
        float x0 = x[bloc][k], x1 = x[bloc][k + 1], x2 = x[bloc][k + 2], x3 = x[bloc][k + 3];
#pragma unroll
        for (int i = 0; i < 12; ++i) {
            float4 w4 = *(const float4*)(W_ih + (size_t)(g0 + i * 16) * KIN + k);
            acc[i] += x0 * w4.x + x1 * w4.y + x2 * w4.z + x3 * w4.w;
        }
    }
    float* outp = gi + ((size_t)t * BB + bh * 16 + bloc) * 768;
#pragma unroll
    for (int i = 0; i < 12; ++i) {
        int g = g0 + i * 16;
        outp[g] = acc[i] + b_ih[g];
    }
}

// ---------------- persistent GRU: 32 blocks (one per b) x 768 threads (one per gate-row) ----------------
__global__ void __launch_bounds__(768, 3) k_gru(const float* __restrict__ h0,
                                                const float* __restrict__ gi,
                                                const float* __restrict__ W_hh,
                                                const float* __restrict__ b_hh,
                                                __hip_bfloat16* __restrict__ hA) {
    int b  = blockIdx.x;
    int jp = threadIdx.x;          // 0..767 gate-row
    int j  = jp & 255;
    int g  = jp >> 8;              // 0:r 1:z 2:n
    __shared__ unsigned int h_pk[128];   // h[b,:] as packed bf16 pairs
    __shared__ float hf[256];            // exact f32 h
    __shared__ float r_sh[256];
    __shared__ float z_sh[256];

    unsigned int wreg[128];              // W_hh row jp, packed bf16
    const float* wrow = W_hh + (size_t)jp * HH;
#pragma unroll
    for (int kk = 0; kk < 128; ++kk) {
        float2 w2 = *(const float2*)(wrow + 2 * kk);
        wreg[kk] = packbf(w2.x, w2.y);
    }
    float bias = b_hh[jp];
    if (jp < HH) hf[jp] = h0[b * HH + jp];
    __syncthreads();
    if (jp < 128) h_pk[jp] = packbf(hf[2 * jp], hf[2 * jp + 1]);
    __syncthreads();

    for (int t = 0; t < TT; ++t) {
        float a = 0.f;
#pragma unroll
        for (int kk = 0; kk < 128; kk += 4) {
            uint4 hq = *(const uint4*)&h_pk[kk];
            a = dot2bf(wreg[kk + 0], hq.x, a);
            a = dot2bf(wreg[kk + 1], hq.y, a);
            a = dot2bf(wreg[kk + 2], hq.z, a);
            a = dot2bf(wreg[kk + 3], hq.w, a);
        }
        float gx = gi[((size_t)t * BB + b) * 768 + jp];
        if (g == 0)      r_sh[j] = 1.f / (1.f + __expf(-(gx + a + bias)));
        else if (g == 1) z_sh[j] = 1.f / (1.f + __expf(-(gx + a + bias)));
        __syncthreads();                       // r,z visible
        if (g == 2) {
            float n  = tanhf(gx + r_sh[j] * (a + bias));
            float z  = z_sh[j];
            float hn = (1.f - z) * n + z * hf[j];
            hf[j] = hn;
            hA[((size_t)b * TT + t) * HH + j] = __float2bfloat16(hn);
        }
        __syncthreads();                       // hf updated
        if (jp < 128) h_pk[jp] = packbf(hf[2 * jp], hf[2 * jp + 1]);
        __syncthreads();                       // h_pk ready for next step
    }
}

// ---------------- W_fc f32 -> bf16 ----------------
__global__ void k_cvt(const float* __restrict__ src, __hip_bfloat16* __restrict__ dst) {
    size_t i = ((size_t)blockIdx.x * 256 + threadIdx.x) * 4;
    float4 v = *(const float4*)(src + i);
    __hip_bfloat16 o[4];
    o[0] = __float2bfloat16(v.x);
    o[1] = __float2bfloat16(v.y);
    o[2] = __float2bfloat16(v.z);
    o[3] = __float2bfloat16(v.w);
    *(uint2*)(dst + i) = *(uint2*)o;
}

// ---------------- logits = hA(bf16) @ wfc(bf16)^T + b_fc -> f32 out ----------------
// grid (250 n-tiles, 30 m-tiles), 256 threads (4 waves 2x2), wave tile 64x64, K=256
__global__ void __launch_bounds__(256) k_logits(const __hip_bfloat16* __restrict__ hA,
                                                const __hip_bfloat16* __restrict__ wfc,
                                                const float* __restrict__ b_fc,
                                                float* __restrict__ out) {
    int nt = blockIdx.x;
    int mt = blockIdx.y;
    int wave = threadIdx.x >> 6, lane = threadIdx.x & 63;
    int wm = wave >> 1, wn = wave & 1;
    int m_base = mt * 128 + wm * 64;
    int n_base = nt * 128 + wn * 64;
    int lr = lane & 15;   // row within 16
    int lk = lane >> 4;   // k-group
    f32x4 acc[4][4] = {};
    const short* A  = (const short*)hA;
    const short* Bm = (const short*)wfc;
    for (int k0 = 0; k0 < HH; k0 += 32) {
        bf16x8 a[4], bb[4];
#pragma unroll
        for (int i = 0; i < 4; ++i)
            a[i] = *(const bf16x8*)(A + (size_t)(m_base + i * 16 + lr) * HH + k0 + lk * 8);
#pragma unroll
        for (int j = 0; j < 4; ++j)
            bb[j] = *(const bf16x8*)(Bm + (size_t)(n_base + j * 16 + lr) * HH + k0 + lk * 8);
#pragma unroll
        for (int i = 0; i < 4; ++i)
#pragma unroll
            for (int j = 0; j < 4; ++j)
                acc[i][j] = __builtin_amdgcn_mfma_f32_16x16x32_bf16(a[i], bb[j], acc[i][j], 0, 0, 0);
    }
    // C/D layout: col = lane&15, row = (lane>>4)*4 + reg
#pragma unroll
    for (int i = 0; i < 4; ++i) {
#pragma unroll
        for (int j = 0; j < 4; ++j) {
            int v = n_base + j * 16 + lr;
            float bias = b_fc[v];
#pragma unroll
            for (int q = 0; q < 4; ++q) {
                int m = m_base + i * 16 + lk * 4 + q;
                out[(size_t)m * VV + v] = acc[i][j][q] + bias;
            }
        }
    }
}

extern "C" void kernel_launch(void* const* d_in, const int* in_sizes, int n_in,
                              void* d_out, int out_size, void* d_ws, size_t ws_size,
                              hipStream_t stream) {
    (void)in_sizes; (void)n_in; (void)out_size; (void)ws_size;
    const float* features   = (const float*)d_in[0];
    const float* embeddings = (const float*)d_in[1];
    const float* W_init     = (const float*)d_in[2];
    const float* b_init     = (const float*)d_in[3];
    const float* W_fc2      = (const float*)d_in[4];
    const float* b_fc2      = (const float*)d_in[5];
    const float* W_ih       = (const float*)d_in[6];
    const float* b_ih       = (const float*)d_in[7];
    const float* W_hh       = (const float*)d_in[8];
    const float* b_hh       = (const float*)d_in[9];
    const float* W_fc       = (const float*)d_in[10];
    const float* b_fc       = (const float*)d_in[11];

    char* ws = (char*)d_ws;
    float* mean_f = (float*)(ws);                              // @0       64 KB
    float* feat   = (float*)(ws + 65536);                      // @64K     32 KB
    float* hbuf0  = (float*)(ws + 98304);                      // @96K     32 KB
    __hip_bfloat16* hA = (__hip_bfloat16*)(ws + 131072);       // @128K    1.875 MB (ends 2,097,152)
    float* gi     = (float*)(ws + 2097152);                    // 11.25 MB (ends 13,893,632)
    __hip_bfloat16* wfc = (__hip_bfloat16*)(ws + 2097152);     // overlays gi AFTER gru (16 MB, ends 18,481,152)
    float* outp = (float*)d_out;

    k_meanpool<<<32, 256, 0, stream>>>(features, mean_f);
    k_h0<<<32, 256, 0, stream>>>(mean_f, W_init, b_init, hbuf0);
    k_fc2<<<256, 256, 0, stream>>>(features, W_fc2, b_fc2, feat);
    k_gi<<<dim3(4, 120, 2), 256, 0, stream>>>(embeddings, feat, W_ih, b_ih, gi);
    k_gru<<<32, 768, 0, stream>>>(hbuf0, gi, W_hh, b_hh, hA);
    k_cvt<<<8000, 256, 0, stream>>>(W_fc, wfc);                // gi dead now; overlay is safe
    k_logits<<<dim3(250, 30), 256, 0, stream>>>(hA, wfc, b_fc, outp);
}

// Round 4
// 731.823 us; speedup vs baseline: 2.0199x; 2.0199x over previous
//
#include <hip/hip_runtime.h>
#include <hip/hip_bf16.h>

#define BB 32
#define TT 120
#define EE 300
#define HH 256
#define VV 32000
#define CC 512
#define GG 49      // 7*7
#define KIN 556    // E+H
#define CF 25088   // C*49

typedef __attribute__((ext_vector_type(8))) short bf16x8;
typedef __attribute__((ext_vector_type(4))) float f32x4;

// ---- packed-bf16 helpers ----
__device__ __forceinline__ float bpair_lo(unsigned int u) { return __uint_as_float(u << 16); }
__device__ __forceinline__ float bpair_hi(unsigned int u) { return __uint_as_float(u & 0xFFFF0000u); }

__device__ __forceinline__ unsigned int packbf(float a, float b) {
    union { __hip_bfloat16 h; unsigned short u; } ua, ub;
    ua.h = __float2bfloat16(a); ub.h = __float2bfloat16(b);
    return (unsigned int)ua.u | ((unsigned int)ub.u << 16);
}

#if defined(__has_builtin)
#  if __has_builtin(__builtin_amdgcn_fdot2_f32_bf16)
#    define USE_DOT2 1
#  endif
#endif
#ifndef USE_DOT2
#  define USE_DOT2 0
#endif

#if USE_DOT2
typedef __bf16 bf2_t __attribute__((ext_vector_type(2)));
__device__ __forceinline__ float dot2bf(unsigned int w, unsigned int h, float c) {
    return __builtin_amdgcn_fdot2_f32_bf16(__builtin_bit_cast(bf2_t, w),
                                           __builtin_bit_cast(bf2_t, h), c, false);
}
#else
__device__ __forceinline__ float dot2bf(unsigned int w, unsigned int h, float c) {
    c = fmaf(bpair_lo(w), bpair_lo(h), c);
    c = fmaf(bpair_hi(w), bpair_hi(h), c);
    return c;
}
#endif

// ---------------- mean pool: features [B,C,49] -> mean_f [B,C] ----------------
__global__ void k_meanpool(const float* __restrict__ features, float* __restrict__ mean_f) {
    int b = blockIdx.x;
    for (int c = threadIdx.x; c < CC; c += 256) {
        const float* p = features + (size_t)b * CF + (size_t)c * GG;
        float s = 0.f;
#pragma unroll
        for (int i = 0; i < GG; ++i) s += p[i];
        mean_f[b * CC + c] = s * (1.0f / 49.0f);
    }
}

// ---------------- h0 = mean_f @ W_init.T + b_init -> [B,H] ----------------
__global__ void k_h0(const float* __restrict__ mean_f, const float* __restrict__ W_init,
                     const float* __restrict__ b_init, float* __restrict__ h0) {
    __shared__ float mf[CC];
    int b = blockIdx.x;
    for (int i = threadIdx.x; i < CC; i += 256) mf[i] = mean_f[b * CC + i];
    __syncthreads();
    int h = threadIdx.x;
    const float* w = W_init + (size_t)h * CC;
    float s = 0.f;
    for (int k = 0; k < CC; k += 4) {
        float4 w4 = *(const float4*)(w + k);
        s += mf[k] * w4.x + mf[k + 1] * w4.y + mf[k + 2] * w4.z + mf[k + 3] * w4.w;
    }
    h0[b * HH + h] = s + b_init[h];
}

// ---------------- fc2 stage A: K-split partial GEMM ----------------
// 256 blocks, block kc owns flat-K chunk [kc*98, kc*98+98)
// f_flat[b, i] = features[b*25088 + (i&511)*49 + (i>>9)]
// part[kc][b][h] = sum_{i in chunk} f_flat[b,i] * W_fc2[h,i]
__global__ void __launch_bounds__(256) k_fc2a(const float* __restrict__ features,
                                              const float* __restrict__ W_fc2,
                                              float* __restrict__ part) {
    int kc = blockIdx.x;
    __shared__ float xs[98][BB];
    for (int idx = threadIdx.x; idx < 98 * BB; idx += 256) {
        int ii = idx >> 5, b = idx & 31;
        int ig = kc * 98 + ii;
        int c = ig & 511, p = ig >> 9;
        xs[ii][b] = features[(size_t)b * CF + c * GG + p];
    }
    __syncthreads();
    int h = threadIdx.x;
    float acc[BB];
#pragma unroll
    for (int b = 0; b < BB; ++b) acc[b] = 0.f;
    const float* wp = W_fc2 + (size_t)h * CF + kc * 98;
    for (int ii = 0; ii < 98; ii += 2) {
        float2 w2 = *(const float2*)(wp + ii);
        const float4* x0 = (const float4*)&xs[ii][0];
        const float4* x1 = (const float4*)&xs[ii + 1][0];
#pragma unroll
        for (int q = 0; q < 8; ++q) {
            float4 a4 = x0[q], b4 = x1[q];
            acc[4 * q + 0] += w2.x * a4.x + w2.y * b4.x;
            acc[4 * q + 1] += w2.x * a4.y + w2.y * b4.y;
            acc[4 * q + 2] += w2.x * a4.z + w2.y * b4.z;
            acc[4 * q + 3] += w2.x * a4.w + w2.y * b4.w;
        }
    }
    float* pp = part + (size_t)kc * (BB * 256) + h;
#pragma unroll
    for (int b = 0; b < BB; ++b) pp[b * 256] = acc[b];
}

// ---------------- fc2 stage B: reduce partials -> feat [B,H] ----------------
__global__ void k_fc2b(const float* __restrict__ part, const float* __restrict__ b_fc2,
                       float* __restrict__ feat) {
    int b = blockIdx.x;
    int h = threadIdx.x;
    float s = b_fc2[h];
    const float* pp = part + b * 256 + h;
#pragma unroll 8
    for (int kc = 0; kc < 256; ++kc) s += pp[(size_t)kc * (BB * 256)];
    feat[b * HH + h] = s;
}

// ---------------- gi[t,b,g] = [emb|feat] @ W_ih.T + b_ih -> [T,B,768] f32 ----------------
__global__ void __launch_bounds__(256) k_gi(const float* __restrict__ emb,
                                            const float* __restrict__ feat,
                                            const float* __restrict__ W_ih,
                                            const float* __restrict__ b_ih,
                                            float* __restrict__ gi) {
    int ch = blockIdx.x;   // 0..3
    int t  = blockIdx.y;   // 0..119
    int bh = blockIdx.z;   // 0..1
    __shared__ float x[16][KIN + 1];   // 35.6 KB
    for (int i = threadIdx.x; i < 16 * KIN; i += 256) {
        int r = i / KIN, c = i - r * KIN;
        int bg = bh * 16 + r;
        x[r][c] = (c < EE) ? emb[(size_t)bg * TT * EE + (size_t)t * EE + c]
                           : feat[bg * HH + (c - EE)];
    }
    __syncthreads();
    int bloc = threadIdx.x & 15;
    int jj   = threadIdx.x >> 4;        // 0..15
    int g0   = ch * 192 + jj;
    float acc[12];
#pragma unroll
    for (int i = 0; i < 12; ++i) acc[i] = 0.f;
    for (int k = 0; k < KIN; k += 4) {
        float x0 = x[bloc][k], x1 = x[bloc][k + 1], x2 = x[bloc][k + 2], x3 = x[bloc][k + 3];
#pragma unroll
        for (int i = 0; i < 12; ++i) {
            float4 w4 = *(const float4*)(W_ih + (size_t)(g0 + i * 16) * KIN + k);
            acc[i] += x0 * w4.x + x1 * w4.y + x2 * w4.z + x3 * w4.w;
        }
    }
    float* outp = gi + ((size_t)t * BB + bh * 16 + bloc) * 768;
#pragma unroll
    for (int i = 0; i < 12; ++i) {
        int g = g0 + i * 16;
        outp[g] = acc[i] + b_ih[g];
    }
}

// ---------------- persistent GRU: 32 blocks (one per b) x 768 threads ----------------
__global__ void __launch_bounds__(768, 3) k_gru(const float* __restrict__ h0,
                                                const float* __restrict__ gi,
                                                const float* __restrict__ W_hh,
                                                const float* __restrict__ b_hh,
                                                __hip_bfloat16* __restrict__ hA) {
    int b  = blockIdx.x;
    int jp = threadIdx.x;          // 0..767 gate-row
    int j  = jp & 255;
    int g  = jp >> 8;              // 0:r 1:z 2:n
    __shared__ unsigned int h_pk[128];
    __shared__ float hf[256];
    __shared__ float r_sh[256];
    __shared__ float z_sh[256];

    unsigned int wreg[128];
    const float* wrow = W_hh + (size_t)jp * HH;
#pragma unroll
    for (int kk = 0; kk < 128; ++kk) {
        float2 w2 = *(const float2*)(wrow + 2 * kk);
        wreg[kk] = packbf(w2.x, w2.y);
    }
    float bias = b_hh[jp];
    if (jp < HH) hf[jp] = h0[b * HH + jp];
    __syncthreads();
    if (jp < 128) h_pk[jp] = packbf(hf[2 * jp], hf[2 * jp + 1]);
    __syncthreads();

    for (int t = 0; t < TT; ++t) {
        float a = 0.f;
#pragma unroll
        for (int kk = 0; kk < 128; kk += 4) {
            uint4 hq = *(const uint4*)&h_pk[kk];
            a = dot2bf(wreg[kk + 0], hq.x, a);
            a = dot2bf(wreg[kk + 1], hq.y, a);
            a = dot2bf(wreg[kk + 2], hq.z, a);
            a = dot2bf(wreg[kk + 3], hq.w, a);
        }
        float gx = gi[((size_t)t * BB + b) * 768 + jp];
        if (g == 0)      r_sh[j] = 1.f / (1.f + __expf(-(gx + a + bias)));
        else if (g == 1) z_sh[j] = 1.f / (1.f + __expf(-(gx + a + bias)));
        __syncthreads();
        if (g == 2) {
            float n  = tanhf(gx + r_sh[j] * (a + bias));
            float z  = z_sh[j];
            float hn = (1.f - z) * n + z * hf[j];
            hf[j] = hn;
            hA[((size_t)b * TT + t) * HH + j] = __float2bfloat16(hn);
        }
        __syncthreads();
        if (jp < 128) h_pk[jp] = packbf(hf[2 * jp], hf[2 * jp + 1]);
        __syncthreads();
    }
}

// ---------------- W_fc f32 -> bf16 ----------------
__global__ void k_cvt(const float* __restrict__ src, __hip_bfloat16* __restrict__ dst) {
    size_t i = ((size_t)blockIdx.x * 256 + threadIdx.x) * 4;
    float4 v = *(const float4*)(src + i);
    __hip_bfloat16 o[4];
    o[0] = __float2bfloat16(v.x);
    o[1] = __float2bfloat16(v.y);
    o[2] = __float2bfloat16(v.z);
    o[3] = __float2bfloat16(v.w);
    *(uint2*)(dst + i) = *(uint2*)o;
}

// ---------------- logits = hA(bf16) @ wfc(bf16)^T + b_fc -> f32 out ----------------
__global__ void __launch_bounds__(256) k_logits(const __hip_bfloat16* __restrict__ hA,
                                                const __hip_bfloat16* __restrict__ wfc,
                                                const float* __restrict__ b_fc,
                                                float* __restrict__ out) {
    int nt = blockIdx.x;
    int mt = blockIdx.y;
    int wave = threadIdx.x >> 6, lane = threadIdx.x & 63;
    int wm = wave >> 1, wn = wave & 1;
    int m_base = mt * 128 + wm * 64;
    int n_base = nt * 128 + wn * 64;
    int lr = lane & 15;
    int lk = lane >> 4;
    f32x4 acc[4][4] = {};
    const short* A  = (const short*)hA;
    const short* Bm = (const short*)wfc;
    for (int k0 = 0; k0 < HH; k0 += 32) {
        bf16x8 a[4], bb[4];
#pragma unroll
        for (int i = 0; i < 4; ++i)
            a[i] = *(const bf16x8*)(A + (size_t)(m_base + i * 16 + lr) * HH + k0 + lk * 8);
#pragma unroll
        for (int j = 0; j < 4; ++j)
            bb[j] = *(const bf16x8*)(Bm + (size_t)(n_base + j * 16 + lr) * HH + k0 + lk * 8);
#pragma unroll
        for (int i = 0; i < 4; ++i)
#pragma unroll
            for (int j = 0; j < 4; ++j)
                acc[i][j] = __builtin_amdgcn_mfma_f32_16x16x32_bf16(a[i], bb[j], acc[i][j], 0, 0, 0);
    }
#pragma unroll
    for (int i = 0; i < 4; ++i) {
#pragma unroll
        for (int j = 0; j < 4; ++j) {
            int v = n_base + j * 16 + lr;
            float bias = b_fc[v];
#pragma unroll
            for (int q = 0; q < 4; ++q) {
                int m = m_base + i * 16 + lk * 4 + q;
                out[(size_t)m * VV + v] = acc[i][j][q] + bias;
            }
        }
    }
}

extern "C" void kernel_launch(void* const* d_in, const int* in_sizes, int n_in,
                              void* d_out, int out_size, void* d_ws, size_t ws_size,
                              hipStream_t stream) {
    (void)in_sizes; (void)n_in; (void)out_size; (void)ws_size;
    const float* features   = (const float*)d_in[0];
    const float* embeddings = (const float*)d_in[1];
    const float* W_init     = (const float*)d_in[2];
    const float* b_init     = (const float*)d_in[3];
    const float* W_fc2      = (const float*)d_in[4];
    const float* b_fc2      = (const float*)d_in[5];
    const float* W_ih       = (const float*)d_in[6];
    const float* b_ih       = (const float*)d_in[7];
    const float* W_hh       = (const float*)d_in[8];
    const float* b_hh       = (const float*)d_in[9];
    const float* W_fc       = (const float*)d_in[10];
    const float* b_fc       = (const float*)d_in[11];

    char* ws = (char*)d_ws;
    float* mean_f = (float*)(ws);                              // @0       64 KB
    float* feat   = (float*)(ws + 65536);                      // @64K     32 KB
    float* hbuf0  = (float*)(ws + 98304);                      // @96K     32 KB
    __hip_bfloat16* hA = (__hip_bfloat16*)(ws + 131072);       // @128K    1.875 MB (ends 2,097,152)
    float* gi     = (float*)(ws + 2097152);                    // 11.25 MB (ends 13,893,632)
    float* part   = (float*)(ws + 2097152);                    // 8 MB, overlays gi BEFORE gi is written
    __hip_bfloat16* wfc = (__hip_bfloat16*)(ws + 2097152);     // 16 MB, overlays gi AFTER gru (ends 18,481,152)
    float* outp = (float*)d_out;

    k_meanpool<<<32, 256, 0, stream>>>(features, mean_f);
    k_h0<<<32, 256, 0, stream>>>(mean_f, W_init, b_init, hbuf0);
    k_fc2a<<<256, 256, 0, stream>>>(features, W_fc2, part);
    k_fc2b<<<32, 256, 0, stream>>>(part, b_fc2, feat);
    k_gi<<<dim3(4, 120, 2), 256, 0, stream>>>(embeddings, feat, W_ih, b_ih, gi);
    k_gru<<<32, 768, 0, stream>>>(hbuf0, gi, W_hh, b_hh, hA);
    k_cvt<<<8000, 256, 0, stream>>>(W_fc, wfc);
    k_logits<<<dim3(250, 30), 256, 0, stream>>>(hA, wfc, b_fc, outp);
}

// Round 5
// 640.101 us; speedup vs baseline: 2.3093x; 1.1433x over previous
//
#include <hip/hip_runtime.h>
#include <hip/hip_bf16.h>

#define BB 32
#define TT 120
#define EE 300
#define HH 256
#define VV 32000
#define CC 512
#define GG 49      // 7*7
#define KIN 556    // E+H
#define CF 25088   // C*49

typedef __attribute__((ext_vector_type(8))) short bf16x8;
typedef __attribute__((ext_vector_type(4))) float f32x4;

// ---- packed-bf16 helpers ----
__device__ __forceinline__ float bpair_lo(unsigned int u) { return __uint_as_float(u << 16); }
__device__ __forceinline__ float bpair_hi(unsigned int u) { return __uint_as_float(u & 0xFFFF0000u); }

__device__ __forceinline__ unsigned int packbf(float a, float b) {
    union { __hip_bfloat16 h; unsigned short u; } ua, ub;
    ua.h = __float2bfloat16(a); ub.h = __float2bfloat16(b);
    return (unsigned int)ua.u | ((unsigned int)ub.u << 16);
}

#if defined(__has_builtin)
#  if __has_builtin(__builtin_amdgcn_fdot2_f32_bf16)
#    define USE_DOT2 1
#  endif
#endif
#ifndef USE_DOT2
#  define USE_DOT2 0
#endif

#if USE_DOT2
typedef __bf16 bf2_t __attribute__((ext_vector_type(2)));
__device__ __forceinline__ float dot2bf(unsigned int w, unsigned int h, float c) {
    return __builtin_amdgcn_fdot2_f32_bf16(__builtin_bit_cast(bf2_t, w),
                                           __builtin_bit_cast(bf2_t, h), c, false);
}
#else
__device__ __forceinline__ float dot2bf(unsigned int w, unsigned int h, float c) {
    c = fmaf(bpair_lo(w), bpair_lo(h), c);
    c = fmaf(bpair_hi(w), bpair_hi(h), c);
    return c;
}
#endif

// ---------------- h0 (fused mean-pool): features [B,C,49] -> h0 [B,H] ----------------
__global__ void k_h0f(const float* __restrict__ features, const float* __restrict__ W_init,
                      const float* __restrict__ b_init, float* __restrict__ h0) {
    __shared__ float mf[CC];
    int b = blockIdx.x;
    for (int c = threadIdx.x; c < CC; c += 256) {
        const float* p = features + (size_t)b * CF + (size_t)c * GG;
        float s = 0.f;
#pragma unroll
        for (int i = 0; i < GG; ++i) s += p[i];
        mf[c] = s * (1.0f / 49.0f);
    }
    __syncthreads();
    int h = threadIdx.x;
    const float* w = W_init + (size_t)h * CC;
    float s = 0.f;
    for (int k = 0; k < CC; k += 4) {
        float4 w4 = *(const float4*)(w + k);
        s += mf[k] * w4.x + mf[k + 1] * w4.y + mf[k + 2] * w4.z + mf[k + 3] * w4.w;
    }
    h0[b * HH + h] = s + b_init[h];
}

// ---------------- fc2 stage A: K-split partial GEMM ----------------
__global__ void __launch_bounds__(256) k_fc2a(const float* __restrict__ features,
                                              const float* __restrict__ W_fc2,
                                              float* __restrict__ part) {
    int kc = blockIdx.x;
    __shared__ float xs[98][BB];
    for (int idx = threadIdx.x; idx < 98 * BB; idx += 256) {
        int ii = idx >> 5, b = idx & 31;
        int ig = kc * 98 + ii;
        int c = ig & 511, p = ig >> 9;
        xs[ii][b] = features[(size_t)b * CF + c * GG + p];
    }
    __syncthreads();
    int h = threadIdx.x;
    float acc[BB];
#pragma unroll
    for (int b = 0; b < BB; ++b) acc[b] = 0.f;
    const float* wp = W_fc2 + (size_t)h * CF + kc * 98;
    for (int ii = 0; ii < 98; ii += 2) {
        float2 w2 = *(const float2*)(wp + ii);
        const float4* x0 = (const float4*)&xs[ii][0];
        const float4* x1 = (const float4*)&xs[ii + 1][0];
#pragma unroll
        for (int q = 0; q < 8; ++q) {
            float4 a4 = x0[q], b4 = x1[q];
            acc[4 * q + 0] += w2.x * a4.x + w2.y * b4.x;
            acc[4 * q + 1] += w2.x * a4.y + w2.y * b4.y;
            acc[4 * q + 2] += w2.x * a4.z + w2.y * b4.z;
            acc[4 * q + 3] += w2.x * a4.w + w2.y * b4.w;
        }
    }
    float* pp = part + (size_t)kc * (BB * 256) + h;
#pragma unroll
    for (int b = 0; b < BB; ++b) pp[b * 256] = acc[b];
}

// ---------------- fc2 stage B: reduce partials -> feat [B,H] ----------------
__global__ void k_fc2b(const float* __restrict__ part, const float* __restrict__ b_fc2,
                       float* __restrict__ feat) {
    int b = blockIdx.x;
    int h = threadIdx.x;
    float s = b_fc2[h];
    const float* pp = part + b * 256 + h;
#pragma unroll 8
    for (int kc = 0; kc < 256; ++kc) s += pp[(size_t)kc * (BB * 256)];
    feat[b * HH + h] = s;
}

// ---------------- gi[t,b,g] = [emb|feat] @ W_ih.T + b_ih -> [T,B,768] f32 ----------------
__global__ void __launch_bounds__(256) k_gi(const float* __restrict__ emb,
                                            const float* __restrict__ feat,
                                            const float* __restrict__ W_ih,
                                            const float* __restrict__ b_ih,
                                            float* __restrict__ gi) {
    int ch = blockIdx.x;   // 0..3
    int t  = blockIdx.y;   // 0..119
    int bh = blockIdx.z;   // 0..1
    __shared__ float x[16][KIN + 1];
    for (int i = threadIdx.x; i < 16 * KIN; i += 256) {
        int r = i / KIN, c = i - r * KIN;
        int bg = bh * 16 + r;
        x[r][c] = (c < EE) ? emb[(size_t)bg * TT * EE + (size_t)t * EE + c]
                           : feat[bg * HH + (c - EE)];
    }
    __syncthreads();
    int bloc = threadIdx.x & 15;
    int jj   = threadIdx.x >> 4;
    int g0   = ch * 192 + jj;
    float acc[12];
#pragma unroll
    for (int i = 0; i < 12; ++i) acc[i] = 0.f;
    for (int k = 0; k < KIN; k += 4) {
        float x0 = x[bloc][k], x1 = x[bloc][k + 1], x2 = x[bloc][k + 2], x3 = x[bloc][k + 3];
#pragma unroll
        for (int i = 0; i < 12; ++i) {
            float4 w4 = *(const float4*)(W_ih + (size_t)(g0 + i * 16) * KIN + k);
            acc[i] += x0 * w4.x + x1 * w4.y + x2 * w4.z + x3 * w4.w;
        }
    }
    float* outp = gi + ((size_t)t * BB + bh * 16 + bloc) * 768;
#pragma unroll
    for (int i = 0; i < 12; ++i) {
        int g = g0 + i * 16;
        outp[g] = acc[i] + b_ih[g];
    }
}

// ---------------- persistent GRU: 32 blocks (one per b) x 768 threads ----------------
__global__ void __launch_bounds__(768, 3) k_gru(const float* __restrict__ h0,
                                                const float* __restrict__ gi,
                                                const float* __restrict__ W_hh,
                                                const float* __restrict__ b_hh,
                                                __hip_bfloat16* __restrict__ hA) {
    int b  = blockIdx.x;
    int jp = threadIdx.x;
    int j  = jp & 255;
    int g  = jp >> 8;
    __shared__ unsigned int h_pk[128];
    __shared__ float hf[256];
    __shared__ float r_sh[256];
    __shared__ float z_sh[256];

    unsigned int wreg[128];
    const float* wrow = W_hh + (size_t)jp * HH;
#pragma unroll
    for (int kk = 0; kk < 128; ++kk) {
        float2 w2 = *(const float2*)(wrow + 2 * kk);
        wreg[kk] = packbf(w2.x, w2.y);
    }
    float bias = b_hh[jp];
    if (jp < HH) hf[jp] = h0[b * HH + jp];
    __syncthreads();
    if (jp < 128) h_pk[jp] = packbf(hf[2 * jp], hf[2 * jp + 1]);
    __syncthreads();

    for (int t = 0; t < TT; ++t) {
        float a = 0.f;
#pragma unroll
        for (int kk = 0; kk < 128; kk += 4) {
            uint4 hq = *(const uint4*)&h_pk[kk];
            a = dot2bf(wreg[kk + 0], hq.x, a);
            a = dot2bf(wreg[kk + 1], hq.y, a);
            a = dot2bf(wreg[kk + 2], hq.z, a);
            a = dot2bf(wreg[kk + 3], hq.w, a);
        }
        float gx = gi[((size_t)t * BB + b) * 768 + jp];
        if (g == 0)      r_sh[j] = 1.f / (1.f + __expf(-(gx + a + bias)));
        else if (g == 1) z_sh[j] = 1.f / (1.f + __expf(-(gx + a + bias)));
        __syncthreads();
        if (g == 2) {
            float n  = tanhf(gx + r_sh[j] * (a + bias));
            float z  = z_sh[j];
            float hn = (1.f - z) * n + z * hf[j];
            hf[j] = hn;
            hA[((size_t)b * TT + t) * HH + j] = __float2bfloat16(hn);
        }
        __syncthreads();
        if (jp < 128) h_pk[jp] = packbf(hf[2 * jp], hf[2 * jp + 1]);
        __syncthreads();
    }
}

// ---------------- W_fc f32 -> bf16 ----------------
__global__ void k_cvt(const float* __restrict__ src, __hip_bfloat16* __restrict__ dst) {
    size_t i = ((size_t)blockIdx.x * 256 + threadIdx.x) * 4;
    float4 v = *(const float4*)(src + i);
    __hip_bfloat16 o[4];
    o[0] = __float2bfloat16(v.x);
    o[1] = __float2bfloat16(v.y);
    o[2] = __float2bfloat16(v.z);
    o[3] = __float2bfloat16(v.w);
    *(uint2*)(dst + i) = *(uint2*)o;
}

// ---------------- logits: LDS-staged MFMA GEMM, 128x128 tile, BK=64 ----------------
// grid (250 n, 30 m), 256 threads (4 waves 2x2). XOR-swizzled LDS (write-side),
// reg-staged global->LDS with next-K-tile prefetch under MFMA.
__global__ void __launch_bounds__(256) k_logits(const __hip_bfloat16* __restrict__ hA,
                                                const __hip_bfloat16* __restrict__ wfc,
                                                const float* __restrict__ b_fc,
                                                float* __restrict__ out) {
    __shared__ short As[128][64];   // 16 KB  (rows = m)
    __shared__ short Bs[128][64];   // 16 KB  (rows = n/v)
    char* AsB = (char*)As;
    char* BsB = (char*)Bs;

    int nt = blockIdx.x;
    int mt = blockIdx.y;
    int tid  = threadIdx.x;
    int wave = tid >> 6, lane = tid & 63;
    int wm = wave >> 1, wn = wave & 1;
    int lr = lane & 15;
    int lk = lane >> 4;

    // staging geometry: thread -> (row = p*32 + rs, 16B col cs), p = 0..3
    int rs = tid >> 3;        // 0..31
    int cs = tid & 7;         // 0..7 (16B units)
    const short* Ag = (const short*)hA  + (size_t)mt * 128 * HH + (size_t)rs * HH + cs * 8;
    const short* Bg = (const short*)wfc + (size_t)nt * 128 * HH + (size_t)rs * HH + cs * 8;
    int wswz = (cs ^ (rs & 7)) * 16;  // write-side XOR swizzle
    int wofs[4];
#pragma unroll
    for (int p = 0; p < 4; ++p) wofs[p] = (p * 32 + rs) * 128 + wswz;

    f32x4 acc[4][4] = {};

#define LOADT(kt, GA, GB)                                                        \
    do {                                                                         \
        _Pragma("unroll") for (int p = 0; p < 4; ++p)                            \
            GA[p] = *(const bf16x8*)(Ag + (size_t)p * 32 * HH + (kt) * 64);      \
        _Pragma("unroll") for (int p = 0; p < 4; ++p)                            \
            GB[p] = *(const bf16x8*)(Bg + (size_t)p * 32 * HH + (kt) * 64);      \
    } while (0)

#define STORET(GA, GB)                                                           \
    do {                                                                         \
        _Pragma("unroll") for (int p = 0; p < 4; ++p)                            \
            *(bf16x8*)(AsB + wofs[p]) = GA[p];                                   \
        _Pragma("unroll") for (int p = 0; p < 4; ++p)                            \
            *(bf16x8*)(BsB + wofs[p]) = GB[p];                                   \
    } while (0)

#define COMPUTE()                                                                \
    do {                                                                         \
        _Pragma("unroll") for (int kk = 0; kk < 2; ++kk) {                       \
            bf16x8 af[4], bg[4];                                                 \
            _Pragma("unroll") for (int i = 0; i < 4; ++i) {                      \
                int r = wm * 64 + i * 16 + lr;                                   \
                af[i] = *(const bf16x8*)(AsB + r * 128 + (((kk * 4 + lk) ^ (r & 7)) * 16)); \
            }                                                                    \
            _Pragma("unroll") for (int j = 0; j < 4; ++j) {                      \
                int r = wn * 64 + j * 16 + lr;                                   \
                bg[j] = *(const bf16x8*)(BsB + r * 128 + (((kk * 4 + lk) ^ (r & 7)) * 16)); \
            }                                                                    \
            _Pragma("unroll") for (int i = 0; i < 4; ++i)                        \
                _Pragma("unroll") for (int j = 0; j < 4; ++j)                    \
                    acc[i][j] = __builtin_amdgcn_mfma_f32_16x16x32_bf16(af[i], bg[j], acc[i][j], 0, 0, 0); \
        }                                                                        \
    } while (0)

    bf16x8 gA[4], gB[4], gA2[4], gB2[4];
    LOADT(0, gA, gB);
    STORET(gA, gB);   LOADT(1, gA2, gB2); __syncthreads(); COMPUTE(); __syncthreads();
    STORET(gA2, gB2); LOADT(2, gA, gB);   __syncthreads(); COMPUTE(); __syncthreads();
    STORET(gA, gB);   LOADT(3, gA2, gB2); __syncthreads(); COMPUTE(); __syncthreads();
    STORET(gA2, gB2);                     __syncthreads(); COMPUTE();

#undef LOADT
#undef STORET
#undef COMPUTE

    int m_base = mt * 128 + wm * 64;
    int n_base = nt * 128 + wn * 64;
#pragma unroll
    for (int i = 0; i < 4; ++i) {
#pragma unroll
        for (int j = 0; j < 4; ++j) {
            int v = n_base + j * 16 + lr;
            float bias = b_fc[v];
#pragma unroll
            for (int q = 0; q < 4; ++q) {
                int m = m_base + i * 16 + lk * 4 + q;
                out[(size_t)m * VV + v] = acc[i][j][q] + bias;
            }
        }
    }
}

extern "C" void kernel_launch(void* const* d_in, const int* in_sizes, int n_in,
                              void* d_out, int out_size, void* d_ws, size_t ws_size,
                              hipStream_t stream) {
    (void)in_sizes; (void)n_in; (void)out_size; (void)ws_size;
    const float* features   = (const float*)d_in[0];
    const float* embeddings = (const float*)d_in[1];
    const float* W_init     = (const float*)d_in[2];
    const float* b_init     = (const float*)d_in[3];
    const float* W_fc2      = (const float*)d_in[4];
    const float* b_fc2      = (const float*)d_in[5];
    const float* W_ih       = (const float*)d_in[6];
    const float* b_ih       = (const float*)d_in[7];
    const float* W_hh       = (const float*)d_in[8];
    const float* b_hh       = (const float*)d_in[9];
    const float* W_fc       = (const float*)d_in[10];
    const float* b_fc       = (const float*)d_in[11];

    char* ws = (char*)d_ws;
    float* feat   = (float*)(ws + 65536);                      // 32 KB
    float* hbuf0  = (float*)(ws + 98304);                      // 32 KB
    __hip_bfloat16* hA = (__hip_bfloat16*)(ws + 131072);       // 1.875 MB (ends 2,097,152)
    float* gi     = (float*)(ws + 2097152);                    // 11.25 MB
    float* part   = (float*)(ws + 2097152);                    // 8 MB, overlays gi BEFORE gi is written
    __hip_bfloat16* wfc = (__hip_bfloat16*)(ws + 2097152);     // 16 MB, overlays gi AFTER gru
    float* outp = (float*)d_out;

    k_h0f<<<32, 256, 0, stream>>>(features, W_init, b_init, hbuf0);
    k_fc2a<<<256, 256, 0, stream>>>(features, W_fc2, part);
    k_fc2b<<<32, 256, 0, stream>>>(part, b_fc2, feat);
    k_gi<<<dim3(4, 120, 2), 256, 0, stream>>>(embeddings, feat, W_ih, b_ih, gi);
    k_gru<<<32, 768, 0, stream>>>(hbuf0, gi, W_hh, b_hh, hA);
    k_cvt<<<8000, 256, 0, stream>>>(W_fc, wfc);
    k_logits<<<dim3(250, 30), 256, 0, stream>>>(hA, wfc, b_fc, outp);
}